// Round 1
// baseline (631.638 us; speedup 1.0000x reference)
//
#include <hip/hip_runtime.h>
#include <hip/hip_bf16.h>

#define NB 16
#define NT 512
#define ND 256
#define NH 4
#define NHD 64
#define NTAG 64

__device__ __forceinline__ float ldf(const void* p, int isbf, long i) {
  return isbf ? __bfloat162float(((const __hip_bfloat16*)p)[i])
              : ((const float*)p)[i];
}

// ---------------- dtype detection ----------------
// View float buffer as bf16: f32 data -> low-half words have random exponents
// (values >1e4 guaranteed over 32K samples). Real bf16 N(0,1) maxes ~5.
__global__ void k_detect(const void* emb, int n, int* flag) {
  __shared__ int s_big;
  if (threadIdx.x == 0) s_big = 0;
  __syncthreads();
  const __hip_bfloat16* p = (const __hip_bfloat16*)emb;
  int big = 0;
  for (int i = threadIdx.x; i < n; i += blockDim.x) {
    float v = __bfloat162float(p[i]);
    if (fabsf(v) > 1e4f) big = 1;
  }
  if (big) atomicOr(&s_big, 1);
  __syncthreads();
  if (threadIdx.x == 0) *flag = s_big ? 0 : 1;  // 1 => inputs are bf16
}

// ---------------- embedding gather ----------------
__global__ __launch_bounds__(64) void k_gather(const int* __restrict__ sent,
                                               const void* emb,
                                               float* __restrict__ X,
                                               const int* flagp) {
  int row = blockIdx.x;            // b*T + t
  int isbf = *flagp;
  long tok = (long)sent[row];
  long src = tok * ND;
  int d0 = threadIdx.x * 4;
  float4 r;
  r.x = ldf(emb, isbf, src + d0 + 0);
  r.y = ldf(emb, isbf, src + d0 + 1);
  r.z = ldf(emb, isbf, src + d0 + 2);
  r.w = ldf(emb, isbf, src + d0 + 3);
  *(float4*)&X[(long)row * ND + d0] = r;
}

// ---------------- GEMM: Y = X @ W^T + b ----------------
// M=8192, N=256 (4 n-tiles), K=256. storeAttn: write (b,h,t,hd) layout.
__global__ __launch_bounds__(256) void k_gemm(
    const float* __restrict__ A, const void* W0, const void* W1, const void* W2,
    const void* B0, const void* B1, const void* B2,
    float* O0, float* O1, float* O2, const int* flagp, int storeAttn) {
  __shared__ __align__(16) float As[16][68];
  __shared__ __align__(16) float Bs[16][68];
  int isbf = *flagp;
  int z = blockIdx.z;
  const void* W = (z == 0) ? W0 : (z == 1) ? W1 : W2;
  const void* Bb = (z == 0) ? B0 : (z == 1) ? B1 : B2;
  float* O = (z == 0) ? O0 : (z == 1) ? O1 : O2;

  int tid = threadIdx.x;
  int tx = tid & 15, ty = tid >> 4;
  int row0 = blockIdx.x * 64;
  int col0 = blockIdx.y * 64;

  float acc[4][4];
#pragma unroll
  for (int i = 0; i < 4; ++i)
#pragma unroll
    for (int j = 0; j < 4; ++j) acc[i][j] = 0.f;

  int r = tid >> 2;             // 0..63
  int kq = (tid & 3) << 2;      // 0,4,8,12

  for (int k0 = 0; k0 < 256; k0 += 16) {
    float4 a4 = *(const float4*)&A[(long)(row0 + r) * 256 + k0 + kq];
    As[kq + 0][r] = a4.x; As[kq + 1][r] = a4.y;
    As[kq + 2][r] = a4.z; As[kq + 3][r] = a4.w;
    long wb = (long)(col0 + r) * 256 + k0 + kq;
    Bs[kq + 0][r] = ldf(W, isbf, wb + 0);
    Bs[kq + 1][r] = ldf(W, isbf, wb + 1);
    Bs[kq + 2][r] = ldf(W, isbf, wb + 2);
    Bs[kq + 3][r] = ldf(W, isbf, wb + 3);
    __syncthreads();
#pragma unroll
    for (int kk = 0; kk < 16; ++kk) {
      float4 av4 = *(const float4*)&As[kk][ty * 4];
      float4 bv4 = *(const float4*)&Bs[kk][tx * 4];
      float av[4] = {av4.x, av4.y, av4.z, av4.w};
      float bv[4] = {bv4.x, bv4.y, bv4.z, bv4.w};
#pragma unroll
      for (int i = 0; i < 4; ++i)
#pragma unroll
        for (int j = 0; j < 4; ++j) acc[i][j] += av[i] * bv[j];
    }
    __syncthreads();
  }

  float bvv[4];
#pragma unroll
  for (int j = 0; j < 4; ++j) bvv[j] = ldf(Bb, isbf, col0 + tx * 4 + j);

#pragma unroll
  for (int i = 0; i < 4; ++i) {
    int row = row0 + ty * 4 + i;
    float4 r4;
    r4.x = acc[i][0] + bvv[0]; r4.y = acc[i][1] + bvv[1];
    r4.z = acc[i][2] + bvv[2]; r4.w = acc[i][3] + bvv[3];
    if (storeAttn) {
      int bb = row >> 9, tt = row & 511;
      // h == blockIdx.y since BN == HD == 64
      *(float4*)&O[(((long)(bb * 4 + blockIdx.y)) * 512 + tt) * 64 + tx * 4] = r4;
    } else {
      *(float4*)&O[(long)row * 256 + col0 + tx * 4] = r4;
    }
  }
}

// ---------------- flash attention ----------------
// grid: (64 bh, 8 q-tiles). Q/K/V: [bh][t][d]. Out AO: [b*T+t][h*64+d].
__global__ __launch_bounds__(256) void k_attn(const float* __restrict__ Qg,
                                              const float* __restrict__ Kg,
                                              const float* __restrict__ Vg,
                                              float* __restrict__ AO) {
  __shared__ __align__(16) float Qs[64][68];   // [d][m]
  __shared__ __align__(16) float KPs[64][68];  // [d][n] then reused as P [n][m]
  __shared__ __align__(16) float Vs[64][68];   // [n][d]
  int tid = threadIdx.x;
  int tx = tid & 15, ty = tid >> 4;
  int bh = blockIdx.x, qt = blockIdx.y;
  const float* Qb = Qg + ((long)bh * 512 + qt * 64) * 64;

#pragma unroll
  for (int c = 0; c < 4; ++c) {
    int idx = tid + c * 256;          // float4 index 0..1023
    int m = idx >> 4, dq = (idx & 15) << 2;
    float4 q4 = *(const float4*)&Qb[m * 64 + dq];
    Qs[dq + 0][m] = q4.x; Qs[dq + 1][m] = q4.y;
    Qs[dq + 2][m] = q4.z; Qs[dq + 3][m] = q4.w;
  }

  float o[4][4];
  float mrow[4], lrow[4];
#pragma unroll
  for (int i = 0; i < 4; ++i) {
    mrow[i] = -1e30f; lrow[i] = 0.f;
#pragma unroll
    for (int j = 0; j < 4; ++j) o[i][j] = 0.f;
  }

  for (int kt = 0; kt < 8; ++kt) {
    __syncthreads();  // protect prev-iter LDS reads (and initial Qs writes)
    const float* Kb = Kg + ((long)bh * 512 + kt * 64) * 64;
    const float* Vb = Vg + ((long)bh * 512 + kt * 64) * 64;
#pragma unroll
    for (int c = 0; c < 4; ++c) {
      int idx = tid + c * 256;
      int n = idx >> 4, dq = (idx & 15) << 2;
      float4 k4 = *(const float4*)&Kb[n * 64 + dq];
      KPs[dq + 0][n] = k4.x; KPs[dq + 1][n] = k4.y;
      KPs[dq + 2][n] = k4.z; KPs[dq + 3][n] = k4.w;
      *(float4*)&Vs[n][dq] = *(const float4*)&Vb[n * 64 + dq];
    }
    __syncthreads();

    float s[4][4];
#pragma unroll
    for (int i = 0; i < 4; ++i)
#pragma unroll
      for (int j = 0; j < 4; ++j) s[i][j] = 0.f;
#pragma unroll 8
    for (int d = 0; d < 64; ++d) {
      float4 a4 = *(const float4*)&Qs[d][ty * 4];
      float4 b4 = *(const float4*)&KPs[d][tx * 4];
      float av[4] = {a4.x, a4.y, a4.z, a4.w};
      float bv[4] = {b4.x, b4.y, b4.z, b4.w};
#pragma unroll
      for (int i = 0; i < 4; ++i)
#pragma unroll
        for (int j = 0; j < 4; ++j) s[i][j] += av[i] * bv[j];
    }
#pragma unroll
    for (int i = 0; i < 4; ++i)
#pragma unroll
      for (int j = 0; j < 4; ++j) s[i][j] *= 0.125f;

    float rmax[4];
#pragma unroll
    for (int i = 0; i < 4; ++i)
      rmax[i] = fmaxf(fmaxf(s[i][0], s[i][1]), fmaxf(s[i][2], s[i][3]));
#pragma unroll
    for (int off = 1; off < 16; off <<= 1)
#pragma unroll
      for (int i = 0; i < 4; ++i)
        rmax[i] = fmaxf(rmax[i], __shfl_xor(rmax[i], off));

    float alpha[4], psum[4];
#pragma unroll
    for (int i = 0; i < 4; ++i) {
      float mnew = fmaxf(mrow[i], rmax[i]);
      alpha[i] = __expf(mrow[i] - mnew);
      mrow[i] = mnew;
      float ps = 0.f;
#pragma unroll
      for (int j = 0; j < 4; ++j) {
        s[i][j] = __expf(s[i][j] - mnew);
        ps += s[i][j];
      }
      psum[i] = ps;
    }
#pragma unroll
    for (int off = 1; off < 16; off <<= 1)
#pragma unroll
      for (int i = 0; i < 4; ++i) psum[i] += __shfl_xor(psum[i], off);
#pragma unroll
    for (int i = 0; i < 4; ++i) {
      lrow[i] = lrow[i] * alpha[i] + psum[i];
#pragma unroll
      for (int j = 0; j < 4; ++j) o[i][j] *= alpha[i];
    }

    __syncthreads();  // all K reads done -> reuse KPs as P
#pragma unroll
    for (int i = 0; i < 4; ++i)
#pragma unroll
      for (int j = 0; j < 4; ++j) KPs[tx * 4 + j][ty * 4 + i] = s[i][j];
    __syncthreads();

#pragma unroll 8
    for (int n = 0; n < 64; ++n) {
      float4 p4 = *(const float4*)&KPs[n][ty * 4];
      float4 v4 = *(const float4*)&Vs[n][tx * 4];
      float pa[4] = {p4.x, p4.y, p4.z, p4.w};
      float va[4] = {v4.x, v4.y, v4.z, v4.w};
#pragma unroll
      for (int i = 0; i < 4; ++i)
#pragma unroll
        for (int j = 0; j < 4; ++j) o[i][j] += pa[i] * va[j];
    }
  }

  int b = bh >> 2, h = bh & 3;
#pragma unroll
  for (int i = 0; i < 4; ++i) {
    float inv = 1.f / lrow[i];
    int trow = qt * 64 + ty * 4 + i;
    float4 r4;
    r4.x = o[i][0] * inv; r4.y = o[i][1] * inv;
    r4.z = o[i][2] * inv; r4.w = o[i][3] * inv;
    *(float4*)&AO[((long)(b * 512 + trow)) * 256 + h * 64 + tx * 4] = r4;
  }
}

// ---------------- gate-angle precompute ----------------
// P[t][b][g*4+w] = bG[w] + thG[w] + sum_d ATTN[b*T+t][d] * WG[w][d]
__global__ __launch_bounds__(256) void k_precomp(
    const float* __restrict__ ATTN, const void* Wf, const void* Wi,
    const void* Wg, const void* Wo2, const void* bF, const void* bI,
    const void* bG, const void* bO, const void* thF, const void* thI,
    const void* thG, const void* thO, float* __restrict__ P,
    const int* flagp) {
  __shared__ __align__(16) float Xs[16][260];
  __shared__ float Ws[16][260];
  __shared__ float ab[16];
  int isbf = *flagp;
  int tid = threadIdx.x;
  int r0 = blockIdx.x * 16;

#pragma unroll
  for (int c = 0; c < 4; ++c) {
    int fi = tid + c * 256;       // float4 idx 0..1023
    int r = fi >> 6, dq = (fi & 63) << 2;
    *(float4*)&Xs[r][dq] = *(const float4*)&ATTN[(long)(r0 + r) * 256 + dq];
  }
  for (int e = tid; e < 4096; e += 256) {
    int out = e >> 8, k = e & 255;
    int gate = out >> 2, w = out & 3;
    const void* Wsel = (gate == 0) ? Wf : (gate == 1) ? Wi : (gate == 2) ? Wg : Wo2;
    Ws[out][k] = ldf(Wsel, isbf, (long)w * 260 + k);
  }
  if (tid < 16) {
    int gate = tid >> 2, w = tid & 3;
    const void* bsel = (gate == 0) ? bF : (gate == 1) ? bI : (gate == 2) ? bG : bO;
    const void* tsel = (gate == 0) ? thF : (gate == 1) ? thI : (gate == 2) ? thG : thO;
    ab[tid] = ldf(bsel, isbf, w) + ldf(tsel, isbf, w);
  }
  __syncthreads();

  int r = tid >> 4, oi = tid & 15;
  float acc = ab[oi];
#pragma unroll 8
  for (int k = 0; k < 256; ++k) acc += Xs[r][k] * Ws[oi][k];
  int rg = r0 + r;
  int b = rg >> 9, t = rg & 511;
  P[(long)t * 256 + b * 16 + oi] = acc;
}

// ---------------- sequential scan (single wave) ----------------
// lane = b*4 + G. Closed-form 4-qubit circuit: with phi_w = angle_w + theta_w
// (theta folded into P): out0=c1c2c3, out1=c0c1, out2=c0c1c2, out3=c0c1c2c3.
__global__ __launch_bounds__(64) void k_scan(const float* __restrict__ P,
                                             const void* Wf, const void* Wi,
                                             const void* Wg, const void* Wo2,
                                             float* __restrict__ HS,
                                             const int* flagp) {
  int lane = threadIdx.x;
  int b = lane >> 2, G = lane & 3;
  int isbf = *flagp;
  const void* Wsel = (G == 0) ? Wf : (G == 1) ? Wi : (G == 2) ? Wg : Wo2;
  float rec[4][4];
#pragma unroll
  for (int w = 0; w < 4; ++w)
#pragma unroll
    for (int j = 0; j < 4; ++j)
      rec[w][j] = ldf(Wsel, isbf, (long)w * 260 + 256 + j);
  float kk = (G == 2) ? 2.f : 1.f;   // tanh = 2*sigmoid(2x)-1
  float km1 = kk - 1.f;
  float hx[4] = {0.f, 0.f, 0.f, 0.f};
  float cx[4] = {0.f, 0.f, 0.f, 0.f};
  int base = lane & ~3;
  float4 pc = *(const float4*)&P[b * 16 + G * 4];
  for (int t = 0; t < 512; ++t) {
    int tn = (t + 1) & 511;
    float4 pn = *(const float4*)&P[(long)tn * 256 + b * 16 + G * 4];
    float a0 = pc.x + rec[0][0]*hx[0] + rec[0][1]*hx[1] + rec[0][2]*hx[2] + rec[0][3]*hx[3];
    float a1 = pc.y + rec[1][0]*hx[0] + rec[1][1]*hx[1] + rec[1][2]*hx[2] + rec[1][3]*hx[3];
    float a2 = pc.z + rec[2][0]*hx[0] + rec[2][1]*hx[1] + rec[2][2]*hx[2] + rec[2][3]*hx[3];
    float a3 = pc.w + rec[3][0]*hx[0] + rec[3][1]*hx[1] + rec[3][2]*hx[2] + rec[3][3]*hx[3];
    float c0 = __cosf(a0), c1 = __cosf(a1), c2 = __cosf(a2), c3 = __cosf(a3);
    float v[4];
    float t01 = c0 * c1;
    v[0] = c1 * c2 * c3;
    v[1] = t01;
    v[2] = t01 * c2;
    v[3] = v[2] * c3;
    float vals[4];
#pragma unroll
    for (int w = 0; w < 4; ++w) {
      float sg = 1.f / (1.f + __expf(-kk * v[w]));
      vals[w] = kk * sg - km1;
    }
    float fv[4], iv[4], gv[4], ov[4];
#pragma unroll
    for (int w = 0; w < 4; ++w) {
      fv[w] = __shfl(vals[w], base + 0);
      iv[w] = __shfl(vals[w], base + 1);
      gv[w] = __shfl(vals[w], base + 2);
      ov[w] = __shfl(vals[w], base + 3);
    }
#pragma unroll
    for (int w = 0; w < 4; ++w) {
      cx[w] = fv[w] * cx[w] + iv[w] * gv[w];
      float th = 2.f / (1.f + __expf(-2.f * cx[w])) - 1.f;
      hx[w] = ov[w] * th;
    }
    float hout = (G == 0) ? hx[0] : (G == 1) ? hx[1] : (G == 2) ? hx[2] : hx[3];
    HS[t * 64 + b * 4 + G] = hout;
    pc = pn;
  }
}

// ---------------- logits + log_softmax ----------------
__global__ __launch_bounds__(64) void k_final(const float* __restrict__ HS,
                                              const void* Wt, const void* Bt,
                                              void* outp, const int* flagp) {
  int r = blockIdx.x;              // b*512 + t
  int b = r >> 9, t = r & 511;
  int j = threadIdx.x;             // tag
  int isbf = *flagp;
  const float* h = &HS[t * 64 + b * 4];
  float h0 = h[0], h1 = h[1], h2 = h[2], h3 = h[3];
  float lg = ldf(Bt, isbf, j)
           + h0 * ldf(Wt, isbf, (long)j * 4 + 0)
           + h1 * ldf(Wt, isbf, (long)j * 4 + 1)
           + h2 * ldf(Wt, isbf, (long)j * 4 + 2)
           + h3 * ldf(Wt, isbf, (long)j * 4 + 3);
  float mx = lg;
#pragma unroll
  for (int off = 1; off < 64; off <<= 1) mx = fmaxf(mx, __shfl_xor(mx, off));
  float e = __expf(lg - mx);
  float ssum = e;
#pragma unroll
  for (int off = 1; off < 64; off <<= 1) ssum += __shfl_xor(ssum, off);
  float res = lg - mx - __logf(ssum);
  long oidx = (long)r * 64 + j;
  if (isbf) ((__hip_bfloat16*)outp)[oidx] = __float2bfloat16(res);
  else ((float*)outp)[oidx] = res;
}

extern "C" void kernel_launch(void* const* d_in, const int* in_sizes, int n_in,
                              void* d_out, int out_size, void* d_ws, size_t ws_size,
                              hipStream_t stream) {
  const int* sent = (const int*)d_in[0];
  const void* emb = d_in[1];
  const void* Wq = d_in[2];  const void* bq = d_in[3];
  const void* Wk = d_in[4];  const void* bk = d_in[5];
  const void* Wv = d_in[6];  const void* bv = d_in[7];
  const void* Wo = d_in[8];  const void* bo = d_in[9];
  const void* Wf = d_in[10]; const void* bF = d_in[11]; const void* thF = d_in[12];
  const void* Wi = d_in[13]; const void* bI = d_in[14]; const void* thI = d_in[15];
  const void* Wg = d_in[16]; const void* bG = d_in[17]; const void* thG = d_in[18];
  const void* Wo2 = d_in[19]; const void* bO = d_in[20]; const void* thO = d_in[21];
  const void* Wt = d_in[22]; const void* Bt = d_in[23];

  int* flag = (int*)d_ws;
  float* base = (float*)((char*)d_ws + 256);
  float* X  = base;                 // 2M floats; later reused as AO
  float* Qb = X + 2097152;          // later reused as ATTN
  float* Kb = Qb + 2097152;
  float* Vb = Kb + 2097152;
  float* Pp = Vb + 2097152;         // 131072 floats
  float* HS = Pp + 131072;          // 32768 floats

  k_detect<<<1, 256, 0, stream>>>(emb, 32768, flag);
  k_gather<<<8192, 64, 0, stream>>>(sent, emb, X, flag);
  dim3 gq(128, 4, 3);
  k_gemm<<<gq, 256, 0, stream>>>(X, Wq, Wk, Wv, bq, bk, bv, Qb, Kb, Vb, flag, 1);
  dim3 ga(64, 8, 1);
  k_attn<<<ga, 256, 0, stream>>>(Qb, Kb, Vb, X);     // AO -> X buffer
  dim3 gw(128, 4, 1);
  k_gemm<<<gw, 256, 0, stream>>>(X, Wo, Wo, Wo, bo, bo, bo, Qb, Qb, Qb, flag, 0); // ATTN -> Qb
  k_precomp<<<512, 256, 0, stream>>>(Qb, Wf, Wi, Wg, Wo2, bF, bI, bG, bO,
                                     thF, thI, thG, thO, Pp, flag);
  k_scan<<<1, 64, 0, stream>>>(Pp, Wf, Wi, Wg, Wo2, HS, flag);
  k_final<<<8192, 64, 0, stream>>>(HS, Wt, Bt, d_out, flag);
}

// Round 2
// 572.232 us; speedup vs baseline: 1.1038x; 1.1038x over previous
//
#include <hip/hip_runtime.h>
#include <hip/hip_bf16.h>

#define NB 16
#define NT 512
#define ND 256
#define NH 4
#define NHD 64
#define NTAG 64

__device__ __forceinline__ float ldf(const void* p, int isbf, long i) {
  return isbf ? __bfloat162float(((const __hip_bfloat16*)p)[i])
              : ((const float*)p)[i];
}

template <int CTRL>
__device__ __forceinline__ float dppf(float v) {
  return __int_as_float(
      __builtin_amdgcn_update_dpp(0, __float_as_int(v), CTRL, 0xF, 0xF, false));
}

// ---------------- dtype detection + DPP direction probe ----------------
// flag[0]: 1 => inputs are bf16. flag[1]: 1 => row_ror:4 reads from lane+4.
__global__ void k_detect(const void* emb, int n, int* flag) {
  __shared__ int s_big;
  if (threadIdx.x == 0) s_big = 0;
  __syncthreads();
  const __hip_bfloat16* p = (const __hip_bfloat16*)emb;
  int big = 0;
  for (int i = threadIdx.x; i < n; i += blockDim.x) {
    float v = __bfloat162float(p[i]);
    if (fabsf(v) > 1e4f) big = 1;
  }
  if (big) atomicOr(&s_big, 1);
  // DPP direction probe (wave 0 only writes)
  int lane = threadIdx.x & 63;
  int r = __builtin_amdgcn_update_dpp(0, lane, 0x124, 0xF, 0xF, false); // row_ror:4
  if (threadIdx.x == 5) flag[1] = (r == 9) ? 1 : 0;
  __syncthreads();
  if (threadIdx.x == 0) *flag = s_big ? 0 : 1;
}

// ---------------- embedding gather ----------------
__global__ __launch_bounds__(64) void k_gather(const int* __restrict__ sent,
                                               const void* emb,
                                               float* __restrict__ X,
                                               const int* flagp) {
  int row = blockIdx.x;            // b*T + t
  int isbf = *flagp;
  long tok = (long)sent[row];
  long src = tok * ND;
  int d0 = threadIdx.x * 4;
  float4 r;
  r.x = ldf(emb, isbf, src + d0 + 0);
  r.y = ldf(emb, isbf, src + d0 + 1);
  r.z = ldf(emb, isbf, src + d0 + 2);
  r.w = ldf(emb, isbf, src + d0 + 3);
  *(float4*)&X[(long)row * ND + d0] = r;
}

// ---------------- GEMM: Y = X @ W^T + b ----------------
__global__ __launch_bounds__(256) void k_gemm(
    const float* __restrict__ A, const void* W0, const void* W1, const void* W2,
    const void* B0, const void* B1, const void* B2,
    float* O0, float* O1, float* O2, const int* flagp, int storeAttn) {
  __shared__ __align__(16) float As[16][68];
  __shared__ __align__(16) float Bs[16][68];
  int isbf = *flagp;
  int z = blockIdx.z;
  const void* W = (z == 0) ? W0 : (z == 1) ? W1 : W2;
  const void* Bb = (z == 0) ? B0 : (z == 1) ? B1 : B2;
  float* O = (z == 0) ? O0 : (z == 1) ? O1 : O2;

  int tid = threadIdx.x;
  int tx = tid & 15, ty = tid >> 4;
  int row0 = blockIdx.x * 64;
  int col0 = blockIdx.y * 64;

  float acc[4][4];
#pragma unroll
  for (int i = 0; i < 4; ++i)
#pragma unroll
    for (int j = 0; j < 4; ++j) acc[i][j] = 0.f;

  int r = tid >> 2;
  int kq = (tid & 3) << 2;

  for (int k0 = 0; k0 < 256; k0 += 16) {
    float4 a4 = *(const float4*)&A[(long)(row0 + r) * 256 + k0 + kq];
    As[kq + 0][r] = a4.x; As[kq + 1][r] = a4.y;
    As[kq + 2][r] = a4.z; As[kq + 3][r] = a4.w;
    long wb = (long)(col0 + r) * 256 + k0 + kq;
    Bs[kq + 0][r] = ldf(W, isbf, wb + 0);
    Bs[kq + 1][r] = ldf(W, isbf, wb + 1);
    Bs[kq + 2][r] = ldf(W, isbf, wb + 2);
    Bs[kq + 3][r] = ldf(W, isbf, wb + 3);
    __syncthreads();
#pragma unroll
    for (int kk = 0; kk < 16; ++kk) {
      float4 av4 = *(const float4*)&As[kk][ty * 4];
      float4 bv4 = *(const float4*)&Bs[kk][tx * 4];
      float av[4] = {av4.x, av4.y, av4.z, av4.w};
      float bv[4] = {bv4.x, bv4.y, bv4.z, bv4.w};
#pragma unroll
      for (int i = 0; i < 4; ++i)
#pragma unroll
        for (int j = 0; j < 4; ++j) acc[i][j] += av[i] * bv[j];
    }
    __syncthreads();
  }

  float bvv[4];
#pragma unroll
  for (int j = 0; j < 4; ++j) bvv[j] = ldf(Bb, isbf, col0 + tx * 4 + j);

#pragma unroll
  for (int i = 0; i < 4; ++i) {
    int row = row0 + ty * 4 + i;
    float4 r4;
    r4.x = acc[i][0] + bvv[0]; r4.y = acc[i][1] + bvv[1];
    r4.z = acc[i][2] + bvv[2]; r4.w = acc[i][3] + bvv[3];
    if (storeAttn) {
      int bb = row >> 9, tt = row & 511;
      *(float4*)&O[(((long)(bb * 4 + blockIdx.y)) * 512 + tt) * 64 + tx * 4] = r4;
    } else {
      *(float4*)&O[(long)row * 256 + col0 + tx * 4] = r4;
    }
  }
}

// ---------------- flash attention ----------------
__global__ __launch_bounds__(256) void k_attn(const float* __restrict__ Qg,
                                              const float* __restrict__ Kg,
                                              const float* __restrict__ Vg,
                                              float* __restrict__ AO) {
  __shared__ __align__(16) float Qs[64][68];
  __shared__ __align__(16) float KPs[64][68];
  __shared__ __align__(16) float Vs[64][68];
  int tid = threadIdx.x;
  int tx = tid & 15, ty = tid >> 4;
  int bh = blockIdx.x, qt = blockIdx.y;
  const float* Qb = Qg + ((long)bh * 512 + qt * 64) * 64;

#pragma unroll
  for (int c = 0; c < 4; ++c) {
    int idx = tid + c * 256;
    int m = idx >> 4, dq = (idx & 15) << 2;
    float4 q4 = *(const float4*)&Qb[m * 64 + dq];
    Qs[dq + 0][m] = q4.x; Qs[dq + 1][m] = q4.y;
    Qs[dq + 2][m] = q4.z; Qs[dq + 3][m] = q4.w;
  }

  float o[4][4];
  float mrow[4], lrow[4];
#pragma unroll
  for (int i = 0; i < 4; ++i) {
    mrow[i] = -1e30f; lrow[i] = 0.f;
#pragma unroll
    for (int j = 0; j < 4; ++j) o[i][j] = 0.f;
  }

  for (int kt = 0; kt < 8; ++kt) {
    __syncthreads();
    const float* Kb = Kg + ((long)bh * 512 + kt * 64) * 64;
    const float* Vb = Vg + ((long)bh * 512 + kt * 64) * 64;
#pragma unroll
    for (int c = 0; c < 4; ++c) {
      int idx = tid + c * 256;
      int n = idx >> 4, dq = (idx & 15) << 2;
      float4 k4 = *(const float4*)&Kb[n * 64 + dq];
      KPs[dq + 0][n] = k4.x; KPs[dq + 1][n] = k4.y;
      KPs[dq + 2][n] = k4.z; KPs[dq + 3][n] = k4.w;
      *(float4*)&Vs[n][dq] = *(const float4*)&Vb[n * 64 + dq];
    }
    __syncthreads();

    float s[4][4];
#pragma unroll
    for (int i = 0; i < 4; ++i)
#pragma unroll
      for (int j = 0; j < 4; ++j) s[i][j] = 0.f;
#pragma unroll 8
    for (int d = 0; d < 64; ++d) {
      float4 a4 = *(const float4*)&Qs[d][ty * 4];
      float4 b4 = *(const float4*)&KPs[d][tx * 4];
      float av[4] = {a4.x, a4.y, a4.z, a4.w};
      float bv[4] = {b4.x, b4.y, b4.z, b4.w};
#pragma unroll
      for (int i = 0; i < 4; ++i)
#pragma unroll
        for (int j = 0; j < 4; ++j) s[i][j] += av[i] * bv[j];
    }
#pragma unroll
    for (int i = 0; i < 4; ++i)
#pragma unroll
      for (int j = 0; j < 4; ++j) s[i][j] *= 0.125f;

    float rmax[4];
#pragma unroll
    for (int i = 0; i < 4; ++i)
      rmax[i] = fmaxf(fmaxf(s[i][0], s[i][1]), fmaxf(s[i][2], s[i][3]));
#pragma unroll
    for (int off = 1; off < 16; off <<= 1)
#pragma unroll
      for (int i = 0; i < 4; ++i)
        rmax[i] = fmaxf(rmax[i], __shfl_xor(rmax[i], off));

    float alpha[4], psum[4];
#pragma unroll
    for (int i = 0; i < 4; ++i) {
      float mnew = fmaxf(mrow[i], rmax[i]);
      alpha[i] = __expf(mrow[i] - mnew);
      mrow[i] = mnew;
      float ps = 0.f;
#pragma unroll
      for (int j = 0; j < 4; ++j) {
        s[i][j] = __expf(s[i][j] - mnew);
        ps += s[i][j];
      }
      psum[i] = ps;
    }
#pragma unroll
    for (int off = 1; off < 16; off <<= 1)
#pragma unroll
      for (int i = 0; i < 4; ++i) psum[i] += __shfl_xor(psum[i], off);
#pragma unroll
    for (int i = 0; i < 4; ++i) {
      lrow[i] = lrow[i] * alpha[i] + psum[i];
#pragma unroll
      for (int j = 0; j < 4; ++j) o[i][j] *= alpha[i];
    }

    __syncthreads();
#pragma unroll
    for (int i = 0; i < 4; ++i)
#pragma unroll
      for (int j = 0; j < 4; ++j) KPs[tx * 4 + j][ty * 4 + i] = s[i][j];
    __syncthreads();

#pragma unroll 8
    for (int n = 0; n < 64; ++n) {
      float4 p4 = *(const float4*)&KPs[n][ty * 4];
      float4 v4 = *(const float4*)&Vs[n][tx * 4];
      float pa[4] = {p4.x, p4.y, p4.z, p4.w};
      float va[4] = {v4.x, v4.y, v4.z, v4.w};
#pragma unroll
      for (int i = 0; i < 4; ++i)
#pragma unroll
        for (int j = 0; j < 4; ++j) o[i][j] += pa[i] * va[j];
    }
  }

  int b = bh >> 2, h = bh & 3;
#pragma unroll
  for (int i = 0; i < 4; ++i) {
    float inv = 1.f / lrow[i];
    int trow = qt * 64 + ty * 4 + i;
    float4 r4;
    r4.x = o[i][0] * inv; r4.y = o[i][1] * inv;
    r4.z = o[i][2] * inv; r4.w = o[i][3] * inv;
    *(float4*)&AO[((long)(b * 512 + trow)) * 256 + h * 64 + tx * 4] = r4;
  }
}

// ---------------- gate-angle precompute ----------------
__global__ __launch_bounds__(256) void k_precomp(
    const float* __restrict__ ATTN, const void* Wf, const void* Wi,
    const void* Wg, const void* Wo2, const void* bF, const void* bI,
    const void* bG, const void* bO, const void* thF, const void* thI,
    const void* thG, const void* thO, float* __restrict__ P,
    const int* flagp) {
  __shared__ __align__(16) float Xs[16][260];
  __shared__ float Ws[16][260];
  __shared__ float ab[16];
  int isbf = *flagp;
  int tid = threadIdx.x;
  int r0 = blockIdx.x * 16;

#pragma unroll
  for (int c = 0; c < 4; ++c) {
    int fi = tid + c * 256;
    int r = fi >> 6, dq = (fi & 63) << 2;
    *(float4*)&Xs[r][dq] = *(const float4*)&ATTN[(long)(r0 + r) * 256 + dq];
  }
  for (int e = tid; e < 4096; e += 256) {
    int out = e >> 8, k = e & 255;
    int gate = out >> 2, w = out & 3;
    const void* Wsel = (gate == 0) ? Wf : (gate == 1) ? Wi : (gate == 2) ? Wg : Wo2;
    Ws[out][k] = ldf(Wsel, isbf, (long)w * 260 + k);
  }
  if (tid < 16) {
    int gate = tid >> 2, w = tid & 3;
    const void* bsel = (gate == 0) ? bF : (gate == 1) ? bI : (gate == 2) ? bG : bO;
    const void* tsel = (gate == 0) ? thF : (gate == 1) ? thI : (gate == 2) ? thG : thO;
    ab[tid] = ldf(bsel, isbf, w) + ldf(tsel, isbf, w);
  }
  __syncthreads();

  int r = tid >> 4, oi = tid & 15;
  float acc = ab[oi];
#pragma unroll 8
  for (int k = 0; k < 256; ++k) acc += Xs[r][k] * Ws[oi][k];
  int rg = r0 + r;
  int b = rg >> 9, t = rg & 511;
  P[(long)t * 256 + b * 16 + oi] = acc;
}

// ---------------- sequential scan: 4 blocks x 64 lanes ----------------
// lane = q*16 + G*4 + w  (q: batch within block, G: gate, w: wire).
// Closed-form circuit: out0=c1c2c3, out1=c0c1, out2=c0c1c2, out3=c0c1c2c3.
// All cross-lane traffic via DPP (quad_perm + row_ror) — no LDS, no bpermute.
__global__ __launch_bounds__(64) void k_scan(const float* __restrict__ P,
                                             const void* Wf, const void* Wi,
                                             const void* Wg, const void* Wo2,
                                             float* __restrict__ HS,
                                             const int* flagp) {
  int lane = threadIdx.x;
  int q = lane >> 4, G = (lane >> 2) & 3, w = lane & 3;
  int isbf = flagp[0];
  int dir = flagp[1];  // 1 => row_ror:4 reads lane+4 (gate G+1)
  const void* Wsel = (G == 0) ? Wf : (G == 1) ? Wi : (G == 2) ? Wg : Wo2;
  float r0 = ldf(Wsel, isbf, (long)w * 260 + 256 + 0);
  float r1 = ldf(Wsel, isbf, (long)w * 260 + 256 + 1);
  float r2 = ldf(Wsel, isbf, (long)w * 260 + 256 + 2);
  float r3 = ldf(Wsel, isbf, (long)w * 260 + 256 + 3);
  float kk = (G == 2) ? 2.f : 1.f;   // gate g uses tanh = 2*sigmoid(2x)-1
  float km1 = kk - 1.f;
  // role selectors: gate-m value sits at rotation k=(m-G)&3
  int s0 = (0 - G) & 3, s1 = (1 - G) & 3, s2 = (2 - G) & 3, s3 = (3 - G) & 3;
  float h0 = 0.f, h1 = 0.f, h2 = 0.f, h3 = 0.f, cx = 0.f;
  int pbase = blockIdx.x * 64 + lane;  // P[t*256 + pbase], coalesced
  int hbase = blockIdx.x * 16 + q * 4 + w;
  float pc = P[pbase];
  for (int t = 0; t < 512; ++t) {
    float pn = P[((t + 1) & 511) * 256 + pbase];
    float a = pc + r0 * h0 + r1 * h1 + r2 * h2 + r3 * h3;
    float c = __cosf(a);
    float c0 = dppf<0x00>(c), c1 = dppf<0x55>(c);
    float c2 = dppf<0xAA>(c), c3 = dppf<0xFF>(c);
    float p01 = c0 * c1, z23 = c2 * c3;
    float v = (w == 0) ? c1 * z23 : (w == 1) ? p01
            : (w == 2) ? p01 * c2 : p01 * z23;
    float val = kk / (1.f + __expf(-kk * v)) - km1;
    float ra = dppf<0x124>(val);   // row_ror:4
    float rb = dppf<0x128>(val);   // row_ror:8
    float rc = dppf<0x12C>(val);   // row_ror:12
    float rot1 = dir ? ra : rc;
    float rot3 = dir ? rc : ra;
    float f = (s0 == 0) ? val : (s0 == 1) ? rot1 : (s0 == 2) ? rb : rot3;
    float i = (s1 == 0) ? val : (s1 == 1) ? rot1 : (s1 == 2) ? rb : rot3;
    float g = (s2 == 0) ? val : (s2 == 1) ? rot1 : (s2 == 2) ? rb : rot3;
    float o = (s3 == 0) ? val : (s3 == 1) ? rot1 : (s3 == 2) ? rb : rot3;
    cx = f * cx + i * g;
    float th = 2.f / (1.f + __expf(-2.f * cx)) - 1.f;
    float hx = o * th;
    h0 = dppf<0x00>(hx); h1 = dppf<0x55>(hx);
    h2 = dppf<0xAA>(hx); h3 = dppf<0xFF>(hx);
    if (G == 0) HS[t * 64 + hbase] = hx;
    pc = pn;
  }
}

// ---------------- logits + log_softmax ----------------
__global__ __launch_bounds__(64) void k_final(const float* __restrict__ HS,
                                              const void* Wt, const void* Bt,
                                              void* outp, const int* flagp) {
  int r = blockIdx.x;
  int b = r >> 9, t = r & 511;
  int j = threadIdx.x;
  int isbf = *flagp;
  const float* h = &HS[t * 64 + b * 4];
  float h0 = h[0], h1 = h[1], h2 = h[2], h3 = h[3];
  float lg = ldf(Bt, isbf, j)
           + h0 * ldf(Wt, isbf, (long)j * 4 + 0)
           + h1 * ldf(Wt, isbf, (long)j * 4 + 1)
           + h2 * ldf(Wt, isbf, (long)j * 4 + 2)
           + h3 * ldf(Wt, isbf, (long)j * 4 + 3);
  float mx = lg;
#pragma unroll
  for (int off = 1; off < 64; off <<= 1) mx = fmaxf(mx, __shfl_xor(mx, off));
  float e = __expf(lg - mx);
  float ssum = e;
#pragma unroll
  for (int off = 1; off < 64; off <<= 1) ssum += __shfl_xor(ssum, off);
  float res = lg - mx - __logf(ssum);
  long oidx = (long)r * 64 + j;
  if (isbf) ((__hip_bfloat16*)outp)[oidx] = __float2bfloat16(res);
  else ((float*)outp)[oidx] = res;
}

extern "C" void kernel_launch(void* const* d_in, const int* in_sizes, int n_in,
                              void* d_out, int out_size, void* d_ws, size_t ws_size,
                              hipStream_t stream) {
  const int* sent = (const int*)d_in[0];
  const void* emb = d_in[1];
  const void* Wq = d_in[2];  const void* bq = d_in[3];
  const void* Wk = d_in[4];  const void* bk = d_in[5];
  const void* Wv = d_in[6];  const void* bv = d_in[7];
  const void* Wo = d_in[8];  const void* bo = d_in[9];
  const void* Wf = d_in[10]; const void* bF = d_in[11]; const void* thF = d_in[12];
  const void* Wi = d_in[13]; const void* bI = d_in[14]; const void* thI = d_in[15];
  const void* Wg = d_in[16]; const void* bG = d_in[17]; const void* thG = d_in[18];
  const void* Wo2 = d_in[19]; const void* bO = d_in[20]; const void* thO = d_in[21];
  const void* Wt = d_in[22]; const void* Bt = d_in[23];

  int* flag = (int*)d_ws;
  float* base = (float*)((char*)d_ws + 256);
  float* X  = base;                 // 2M floats; later reused as AO
  float* Qb = X + 2097152;          // later reused as ATTN
  float* Kb = Qb + 2097152;
  float* Vb = Kb + 2097152;
  float* Pp = Vb + 2097152;         // 131072 floats
  float* HS = Pp + 131072;          // 32768 floats

  k_detect<<<1, 256, 0, stream>>>(emb, 32768, flag);
  k_gather<<<8192, 64, 0, stream>>>(sent, emb, X, flag);
  dim3 gq(128, 4, 3);
  k_gemm<<<gq, 256, 0, stream>>>(X, Wq, Wk, Wv, bq, bk, bv, Qb, Kb, Vb, flag, 1);
  dim3 ga(64, 8, 1);
  k_attn<<<ga, 256, 0, stream>>>(Qb, Kb, Vb, X);     // AO -> X buffer
  dim3 gw(128, 4, 1);
  k_gemm<<<gw, 256, 0, stream>>>(X, Wo, Wo, Wo, bo, bo, bo, Qb, Qb, Qb, flag, 0);
  k_precomp<<<512, 256, 0, stream>>>(Qb, Wf, Wi, Wg, Wo2, bF, bI, bG, bO,
                                     thF, thI, thG, thO, Pp, flag);
  k_scan<<<4, 64, 0, stream>>>(Pp, Wf, Wi, Wg, Wo2, HS, flag);
  k_final<<<8192, 64, 0, stream>>>(HS, Wt, Bt, d_out, flag);
}

// Round 3
// 524.084 us; speedup vs baseline: 1.2052x; 1.0919x over previous
//
#include <hip/hip_runtime.h>
#include <hip/hip_bf16.h>

#define NB 16
#define NT 512
#define ND 256
#define NH 4
#define NHD 64
#define NTAG 64

__device__ __forceinline__ float ldf(const void* p, int isbf, long i) {
  return isbf ? __bfloat162float(((const __hip_bfloat16*)p)[i])
              : ((const float*)p)[i];
}

template <int CTRL>
__device__ __forceinline__ float dppf(float v) {
  return __int_as_float(
      __builtin_amdgcn_update_dpp(0, __float_as_int(v), CTRL, 0xF, 0xF, false));
}

// ---------------- dtype detection + DPP direction probe ----------------
// flag[0]: 1 => inputs are bf16. flag[1]: 1 => row_ror:4 reads from lane+4.
__global__ void k_detect(const void* emb, int n, int* flag) {
  __shared__ int s_big;
  if (threadIdx.x == 0) s_big = 0;
  __syncthreads();
  const __hip_bfloat16* p = (const __hip_bfloat16*)emb;
  int big = 0;
  for (int i = threadIdx.x; i < n; i += blockDim.x) {
    float v = __bfloat162float(p[i]);
    if (fabsf(v) > 1e4f) big = 1;
  }
  if (big) atomicOr(&s_big, 1);
  int lane = threadIdx.x & 63;
  int r = __builtin_amdgcn_update_dpp(0, lane, 0x124, 0xF, 0xF, false); // row_ror:4
  if (threadIdx.x == 5) flag[1] = (r == 9) ? 1 : 0;
  __syncthreads();
  if (threadIdx.x == 0) *flag = s_big ? 0 : 1;
}

// ---------------- embedding gather ----------------
__global__ __launch_bounds__(64) void k_gather(const int* __restrict__ sent,
                                               const void* emb,
                                               float* __restrict__ X,
                                               const int* flagp) {
  int row = blockIdx.x;            // b*T + t
  int isbf = *flagp;
  long tok = (long)sent[row];
  long src = tok * ND;
  int d0 = threadIdx.x * 4;
  float4 r;
  r.x = ldf(emb, isbf, src + d0 + 0);
  r.y = ldf(emb, isbf, src + d0 + 1);
  r.z = ldf(emb, isbf, src + d0 + 2);
  r.w = ldf(emb, isbf, src + d0 + 3);
  *(float4*)&X[(long)row * ND + d0] = r;
}

// ---------------- GEMM: Y = X @ W^T + b ----------------
__global__ __launch_bounds__(256) void k_gemm(
    const float* __restrict__ A, const void* W0, const void* W1, const void* W2,
    const void* B0, const void* B1, const void* B2,
    float* O0, float* O1, float* O2, const int* flagp, int storeAttn) {
  __shared__ __align__(16) float As[16][68];
  __shared__ __align__(16) float Bs[16][68];
  int isbf = *flagp;
  int z = blockIdx.z;
  const void* W = (z == 0) ? W0 : (z == 1) ? W1 : W2;
  const void* Bb = (z == 0) ? B0 : (z == 1) ? B1 : B2;
  float* O = (z == 0) ? O0 : (z == 1) ? O1 : O2;

  int tid = threadIdx.x;
  int tx = tid & 15, ty = tid >> 4;
  int row0 = blockIdx.x * 64;
  int col0 = blockIdx.y * 64;

  float acc[4][4];
#pragma unroll
  for (int i = 0; i < 4; ++i)
#pragma unroll
    for (int j = 0; j < 4; ++j) acc[i][j] = 0.f;

  int r = tid >> 2;
  int kq = (tid & 3) << 2;

  for (int k0 = 0; k0 < 256; k0 += 16) {
    float4 a4 = *(const float4*)&A[(long)(row0 + r) * 256 + k0 + kq];
    As[kq + 0][r] = a4.x; As[kq + 1][r] = a4.y;
    As[kq + 2][r] = a4.z; As[kq + 3][r] = a4.w;
    long wb = (long)(col0 + r) * 256 + k0 + kq;
    Bs[kq + 0][r] = ldf(W, isbf, wb + 0);
    Bs[kq + 1][r] = ldf(W, isbf, wb + 1);
    Bs[kq + 2][r] = ldf(W, isbf, wb + 2);
    Bs[kq + 3][r] = ldf(W, isbf, wb + 3);
    __syncthreads();
#pragma unroll
    for (int kk = 0; kk < 16; ++kk) {
      float4 av4 = *(const float4*)&As[kk][ty * 4];
      float4 bv4 = *(const float4*)&Bs[kk][tx * 4];
      float av[4] = {av4.x, av4.y, av4.z, av4.w};
      float bv[4] = {bv4.x, bv4.y, bv4.z, bv4.w};
#pragma unroll
      for (int i = 0; i < 4; ++i)
#pragma unroll
        for (int j = 0; j < 4; ++j) acc[i][j] += av[i] * bv[j];
    }
    __syncthreads();
  }

  float bvv[4];
#pragma unroll
  for (int j = 0; j < 4; ++j) bvv[j] = ldf(Bb, isbf, col0 + tx * 4 + j);

#pragma unroll
  for (int i = 0; i < 4; ++i) {
    int row = row0 + ty * 4 + i;
    float4 r4;
    r4.x = acc[i][0] + bvv[0]; r4.y = acc[i][1] + bvv[1];
    r4.z = acc[i][2] + bvv[2]; r4.w = acc[i][3] + bvv[3];
    if (storeAttn) {
      int bb = row >> 9, tt = row & 511;
      *(float4*)&O[(((long)(bb * 4 + blockIdx.y)) * 512 + tt) * 64 + tx * 4] = r4;
    } else {
      *(float4*)&O[(long)row * 256 + col0 + tx * 4] = r4;
    }
  }
}

// ---------------- flash attention ----------------
__global__ __launch_bounds__(256) void k_attn(const float* __restrict__ Qg,
                                              const float* __restrict__ Kg,
                                              const float* __restrict__ Vg,
                                              float* __restrict__ AO) {
  __shared__ __align__(16) float Qs[64][68];
  __shared__ __align__(16) float KPs[64][68];
  __shared__ __align__(16) float Vs[64][68];
  int tid = threadIdx.x;
  int tx = tid & 15, ty = tid >> 4;
  int bh = blockIdx.x, qt = blockIdx.y;
  const float* Qb = Qg + ((long)bh * 512 + qt * 64) * 64;

#pragma unroll
  for (int c = 0; c < 4; ++c) {
    int idx = tid + c * 256;
    int m = idx >> 4, dq = (idx & 15) << 2;
    float4 q4 = *(const float4*)&Qb[m * 64 + dq];
    Qs[dq + 0][m] = q4.x; Qs[dq + 1][m] = q4.y;
    Qs[dq + 2][m] = q4.z; Qs[dq + 3][m] = q4.w;
  }

  float o[4][4];
  float mrow[4], lrow[4];
#pragma unroll
  for (int i = 0; i < 4; ++i) {
    mrow[i] = -1e30f; lrow[i] = 0.f;
#pragma unroll
    for (int j = 0; j < 4; ++j) o[i][j] = 0.f;
  }

  for (int kt = 0; kt < 8; ++kt) {
    __syncthreads();
    const float* Kb = Kg + ((long)bh * 512 + kt * 64) * 64;
    const float* Vb = Vg + ((long)bh * 512 + kt * 64) * 64;
#pragma unroll
    for (int c = 0; c < 4; ++c) {
      int idx = tid + c * 256;
      int n = idx >> 4, dq = (idx & 15) << 2;
      float4 k4 = *(const float4*)&Kb[n * 64 + dq];
      KPs[dq + 0][n] = k4.x; KPs[dq + 1][n] = k4.y;
      KPs[dq + 2][n] = k4.z; KPs[dq + 3][n] = k4.w;
      *(float4*)&Vs[n][dq] = *(const float4*)&Vb[n * 64 + dq];
    }
    __syncthreads();

    float s[4][4];
#pragma unroll
    for (int i = 0; i < 4; ++i)
#pragma unroll
      for (int j = 0; j < 4; ++j) s[i][j] = 0.f;
#pragma unroll 8
    for (int d = 0; d < 64; ++d) {
      float4 a4 = *(const float4*)&Qs[d][ty * 4];
      float4 b4 = *(const float4*)&KPs[d][tx * 4];
      float av[4] = {a4.x, a4.y, a4.z, a4.w};
      float bv[4] = {b4.x, b4.y, b4.z, b4.w};
#pragma unroll
      for (int i = 0; i < 4; ++i)
#pragma unroll
        for (int j = 0; j < 4; ++j) s[i][j] += av[i] * bv[j];
    }
#pragma unroll
    for (int i = 0; i < 4; ++i)
#pragma unroll
      for (int j = 0; j < 4; ++j) s[i][j] *= 0.125f;

    float rmax[4];
#pragma unroll
    for (int i = 0; i < 4; ++i)
      rmax[i] = fmaxf(fmaxf(s[i][0], s[i][1]), fmaxf(s[i][2], s[i][3]));
#pragma unroll
    for (int off = 1; off < 16; off <<= 1)
#pragma unroll
      for (int i = 0; i < 4; ++i)
        rmax[i] = fmaxf(rmax[i], __shfl_xor(rmax[i], off));

    float alpha[4], psum[4];
#pragma unroll
    for (int i = 0; i < 4; ++i) {
      float mnew = fmaxf(mrow[i], rmax[i]);
      alpha[i] = __expf(mrow[i] - mnew);
      mrow[i] = mnew;
      float ps = 0.f;
#pragma unroll
      for (int j = 0; j < 4; ++j) {
        s[i][j] = __expf(s[i][j] - mnew);
        ps += s[i][j];
      }
      psum[i] = ps;
    }
#pragma unroll
    for (int off = 1; off < 16; off <<= 1)
#pragma unroll
      for (int i = 0; i < 4; ++i) psum[i] += __shfl_xor(psum[i], off);
#pragma unroll
    for (int i = 0; i < 4; ++i) {
      lrow[i] = lrow[i] * alpha[i] + psum[i];
#pragma unroll
      for (int j = 0; j < 4; ++j) o[i][j] *= alpha[i];
    }

    __syncthreads();
#pragma unroll
    for (int i = 0; i < 4; ++i)
#pragma unroll
      for (int j = 0; j < 4; ++j) KPs[tx * 4 + j][ty * 4 + i] = s[i][j];
    __syncthreads();

#pragma unroll 8
    for (int n = 0; n < 64; ++n) {
      float4 p4 = *(const float4*)&KPs[n][ty * 4];
      float4 v4 = *(const float4*)&Vs[n][tx * 4];
      float pa[4] = {p4.x, p4.y, p4.z, p4.w};
      float va[4] = {v4.x, v4.y, v4.z, v4.w};
#pragma unroll
      for (int i = 0; i < 4; ++i)
#pragma unroll
        for (int j = 0; j < 4; ++j) o[i][j] += pa[i] * va[j];
    }
  }

  int b = bh >> 2, h = bh & 3;
#pragma unroll
  for (int i = 0; i < 4; ++i) {
    float inv = 1.f / lrow[i];
    int trow = qt * 64 + ty * 4 + i;
    float4 r4;
    r4.x = o[i][0] * inv; r4.y = o[i][1] * inv;
    r4.z = o[i][2] * inv; r4.w = o[i][3] * inv;
    *(float4*)&AO[((long)(b * 512 + trow)) * 256 + h * 64 + tx * 4] = r4;
  }
}

// ---------------- gate-angle precompute ----------------
__global__ __launch_bounds__(256) void k_precomp(
    const float* __restrict__ ATTN, const void* Wf, const void* Wi,
    const void* Wg, const void* Wo2, const void* bF, const void* bI,
    const void* bG, const void* bO, const void* thF, const void* thI,
    const void* thG, const void* thO, float* __restrict__ P,
    const int* flagp) {
  __shared__ __align__(16) float Xs[16][260];
  __shared__ float Ws[16][260];
  __shared__ float ab[16];
  int isbf = *flagp;
  int tid = threadIdx.x;
  int r0 = blockIdx.x * 16;

#pragma unroll
  for (int c = 0; c < 4; ++c) {
    int fi = tid + c * 256;
    int r = fi >> 6, dq = (fi & 63) << 2;
    *(float4*)&Xs[r][dq] = *(const float4*)&ATTN[(long)(r0 + r) * 256 + dq];
  }
  for (int e = tid; e < 4096; e += 256) {
    int out = e >> 8, k = e & 255;
    int gate = out >> 2, w = out & 3;
    const void* Wsel = (gate == 0) ? Wf : (gate == 1) ? Wi : (gate == 2) ? Wg : Wo2;
    Ws[out][k] = ldf(Wsel, isbf, (long)w * 260 + k);
  }
  if (tid < 16) {
    int gate = tid >> 2, w = tid & 3;
    const void* bsel = (gate == 0) ? bF : (gate == 1) ? bI : (gate == 2) ? bG : bO;
    const void* tsel = (gate == 0) ? thF : (gate == 1) ? thI : (gate == 2) ? thG : thO;
    ab[tid] = ldf(bsel, isbf, w) + ldf(tsel, isbf, w);
  }
  __syncthreads();

  int r = tid >> 4, oi = tid & 15;
  float acc = ab[oi];
#pragma unroll 8
  for (int k = 0; k < 256; ++k) acc += Xs[r][k] * Ws[oi][k];
  int rg = r0 + r;
  int b = rg >> 9, t = rg & 511;
  P[(long)t * 256 + b * 16 + oi] = acc;
}

// ---------------- sequential scan: 4 blocks x 64 lanes ----------------
// lane = q*16 + G*4 + w. Deep 8-slot register prefetch of P hides the
// ~900-cycle global-load latency (round-2 counters: 1060 cyc/step, chain
// only ~200). HS accumulates in LDS; coalesced epilogue dump.
__global__ __launch_bounds__(64) void k_scan(const float* __restrict__ P,
                                             const void* Wf, const void* Wi,
                                             const void* Wg, const void* Wo2,
                                             float* __restrict__ HS,
                                             const int* flagp) {
  __shared__ __align__(16) float hsb[512 * 16];
  int lane = threadIdx.x;
  int q = lane >> 4, G = (lane >> 2) & 3, w = lane & 3;
  int isbf = flagp[0];
  int dir = flagp[1];  // 1 => row_ror:4 reads lane+4 (gate G+1)
  const void* Wsel = (G == 0) ? Wf : (G == 1) ? Wi : (G == 2) ? Wg : Wo2;
  float r0 = ldf(Wsel, isbf, (long)w * 260 + 256 + 0);
  float r1 = ldf(Wsel, isbf, (long)w * 260 + 256 + 1);
  float r2 = ldf(Wsel, isbf, (long)w * 260 + 256 + 2);
  float r3 = ldf(Wsel, isbf, (long)w * 260 + 256 + 3);
  float kk = (G == 2) ? 2.f : 1.f;   // gate g uses tanh = 2*sigmoid(2x)-1
  float km1 = kk - 1.f;
  int s0 = (0 - G) & 3, s1 = (1 - G) & 3, s2 = (2 - G) & 3, s3 = (3 - G) & 3;
  float h0 = 0.f, h1 = 0.f, h2 = 0.f, h3 = 0.f, cx = 0.f;
  int pbase = blockIdx.x * 64 + lane;  // P[t*256 + pbase], coalesced
  int hoff = q * 4 + w;

  float pbuf[8];
#pragma unroll
  for (int j = 0; j < 8; ++j) pbuf[j] = P[j * 256 + pbase];

  for (int tb = 0; tb < 512; tb += 8) {
#pragma unroll
    for (int u = 0; u < 8; ++u) {
      int t = tb + u;
      float pc = pbuf[u];
      pbuf[u] = P[((t + 8) & 511) * 256 + pbase];  // keep 8 loads in flight
      float a = pc + r0 * h0 + r1 * h1 + r2 * h2 + r3 * h3;
      float c = __cosf(a);
      float c0 = dppf<0x00>(c), c1 = dppf<0x55>(c);
      float c2 = dppf<0xAA>(c), c3 = dppf<0xFF>(c);
      float p01 = c0 * c1, z23 = c2 * c3;
      float v = (w == 0) ? c1 * z23 : (w == 1) ? p01
              : (w == 2) ? p01 * c2 : p01 * z23;
      float val = kk / (1.f + __expf(-kk * v)) - km1;
      float ra = dppf<0x124>(val);   // row_ror:4
      float rb = dppf<0x128>(val);   // row_ror:8
      float rc = dppf<0x12C>(val);   // row_ror:12
      float rot1 = dir ? ra : rc;
      float rot3 = dir ? rc : ra;
      float f = (s0 == 0) ? val : (s0 == 1) ? rot1 : (s0 == 2) ? rb : rot3;
      float i = (s1 == 0) ? val : (s1 == 1) ? rot1 : (s1 == 2) ? rb : rot3;
      float g = (s2 == 0) ? val : (s2 == 1) ? rot1 : (s2 == 2) ? rb : rot3;
      float o = (s3 == 0) ? val : (s3 == 1) ? rot1 : (s3 == 2) ? rb : rot3;
      cx = f * cx + i * g;
      float th = 2.f / (1.f + __expf(-2.f * cx)) - 1.f;
      float hx = o * th;
      h0 = dppf<0x00>(hx); h1 = dppf<0x55>(hx);
      h2 = dppf<0xAA>(hx); h3 = dppf<0xFF>(hx);
      if (G == 0) hsb[t * 16 + hoff] = hx;
    }
  }
  __syncthreads();
  int hb = blockIdx.x * 16;
#pragma unroll
  for (int i4 = 0; i4 < 32; ++i4) {
    int fi = (i4 * 64 + lane) * 4;       // float index, 16B aligned
    int t = fi >> 4, j = fi & 15;
    *(float4*)&HS[t * 64 + hb + j] = *(const float4*)&hsb[fi];
  }
}

// ---------------- logits + log_softmax ----------------
__global__ __launch_bounds__(64) void k_final(const float* __restrict__ HS,
                                              const void* Wt, const void* Bt,
                                              void* outp, const int* flagp) {
  int r = blockIdx.x;
  int b = r >> 9, t = r & 511;
  int j = threadIdx.x;
  int isbf = *flagp;
  const float* h = &HS[t * 64 + b * 4];
  float h0 = h[0], h1 = h[1], h2 = h[2], h3 = h[3];
  float lg = ldf(Bt, isbf, j)
           + h0 * ldf(Wt, isbf, (long)j * 4 + 0)
           + h1 * ldf(Wt, isbf, (long)j * 4 + 1)
           + h2 * ldf(Wt, isbf, (long)j * 4 + 2)
           + h3 * ldf(Wt, isbf, (long)j * 4 + 3);
  float mx = lg;
#pragma unroll
  for (int off = 1; off < 64; off <<= 1) mx = fmaxf(mx, __shfl_xor(mx, off));
  float e = __expf(lg - mx);
  float ssum = e;
#pragma unroll
  for (int off = 1; off < 64; off <<= 1) ssum += __shfl_xor(ssum, off);
  float res = lg - mx - __logf(ssum);
  long oidx = (long)r * 64 + j;
  if (isbf) ((__hip_bfloat16*)outp)[oidx] = __float2bfloat16(res);
  else ((float*)outp)[oidx] = res;
}

extern "C" void kernel_launch(void* const* d_in, const int* in_sizes, int n_in,
                              void* d_out, int out_size, void* d_ws, size_t ws_size,
                              hipStream_t stream) {
  const int* sent = (const int*)d_in[0];
  const void* emb = d_in[1];
  const void* Wq = d_in[2];  const void* bq = d_in[3];
  const void* Wk = d_in[4];  const void* bk = d_in[5];
  const void* Wv = d_in[6];  const void* bv = d_in[7];
  const void* Wo = d_in[8];  const void* bo = d_in[9];
  const void* Wf = d_in[10]; const void* bF = d_in[11]; const void* thF = d_in[12];
  const void* Wi = d_in[13]; const void* bI = d_in[14]; const void* thI = d_in[15];
  const void* Wg = d_in[16]; const void* bG = d_in[17]; const void* thG = d_in[18];
  const void* Wo2 = d_in[19]; const void* bO = d_in[20]; const void* thO = d_in[21];
  const void* Wt = d_in[22]; const void* Bt = d_in[23];

  int* flag = (int*)d_ws;
  float* base = (float*)((char*)d_ws + 256);
  float* X  = base;                 // 2M floats; later reused as AO
  float* Qb = X + 2097152;          // later reused as ATTN
  float* Kb = Qb + 2097152;
  float* Vb = Kb + 2097152;
  float* Pp = Vb + 2097152;         // 131072 floats
  float* HS = Pp + 131072;          // 32768 floats

  k_detect<<<1, 256, 0, stream>>>(emb, 32768, flag);
  k_gather<<<8192, 64, 0, stream>>>(sent, emb, X, flag);
  dim3 gq(128, 4, 3);
  k_gemm<<<gq, 256, 0, stream>>>(X, Wq, Wk, Wv, bq, bk, bv, Qb, Kb, Vb, flag, 1);
  dim3 ga(64, 8, 1);
  k_attn<<<ga, 256, 0, stream>>>(Qb, Kb, Vb, X);     // AO -> X buffer
  dim3 gw(128, 4, 1);
  k_gemm<<<gw, 256, 0, stream>>>(X, Wo, Wo, Wo, bo, bo, bo, Qb, Qb, Qb, flag, 0);
  k_precomp<<<512, 256, 0, stream>>>(Qb, Wf, Wi, Wg, Wo2, bF, bI, bG, bO,
                                     thF, thI, thG, thO, Pp, flag);
  k_scan<<<4, 64, 0, stream>>>(Pp, Wf, Wi, Wg, Wo2, HS, flag);
  k_final<<<8192, 64, 0, stream>>>(HS, Wt, Bt, d_out, flag);
}